// Round 1
// baseline (324.205 us; speedup 1.0000x reference)
//
#include <hip/hip_runtime.h>

// WaveCell: 16 launches x 16 time steps, temporal blocking with 8-wide
// register patches. Round-7 changes (VALU-issue reduction):
//  - cell update refactored to 7 ops: val = fmaf(G, lap_sum-4y, fmaf(-Ey, yp, Dc*y))
//    with pre-fused coefficients Dc=2e6*ai, Ey=ai*cf, G=ai*cs*inv_h2
//    (same register footprint as ai/cf/cs; laplacian cancellation preserved)
//  - source injection fma guarded by uniform 'hs' (only 24/256 blocks contain
//    the source in their EXT tile)
//  - trapezoid row-gating: step j only needs rows [j+1, 54-j]; with the loop
//    fully unrolled this is a compile-time range -> whole waves (8 rows/wave)
//    skip dead steps via execz (waves 0/6 skip 9 of 16 steps). Guard rows
//    become unread, so guard-row zeroing is removed.
//  - lg==7's cross-row __shfl_down masked to 0 (its source lane may be
//    exec-masked off by row gating; prevents undefined data entering val)

#define NXg 192
#define NYg 192
#define BATCH 4
#define TSTEPS 256
#define CELLS (NXg * NYg)

#define TS 24                   // output tile side
#define KSTEP 16                // time steps per launch
#define EXT 56                  // TS + 2*KSTEP
#define LROWS (EXT + 2)         // rows 1..56 used; 0/57 never read now
#define LPITCH 68               // dwords/row: 4 pad | 56 data | 8 pad; %32==4 spreads banks
#define LSZ (LROWS * LPITCH)
#define NTHREADS 448            // 56 rows x 8 lanes/row = 7 waves

#define SRC_X 96
#define SRC_Y 32

__global__ __launch_bounds__(NTHREADS) void wave_tile_kernel(
    const float* __restrict__ cgp, const float* __restrict__ bgp,
    const float* __restrict__ x, float* __restrict__ out, int t0) {
  __shared__ float buf0[LSZ];
  __shared__ float buf1[LSZ];

  const int tid = threadIdx.x;
  const int lr = tid >> 3;      // local row 0..55
  const int lg = tid & 7;       // 8-wide group in row; lg==7 is the zero lane
  const int bcol = blockIdx.x;  // 0..7
  const int brow = blockIdx.y;  // 0..7
  const int bb = blockIdx.z;    // 0..3
  const int r0 = brow * TS - KSTEP;
  const int c0 = bcol * TS - KSTEP;
  const int obase = bb * TSTEPS * CELLS;
  const float inv_h2 = (float)(1.0 / (2.0 * 1.01 * 1.01 * 1.0e-3 * 1.0e-3));

  const int gr = r0 + lr;
  const int gc = c0 + 8 * lg;  // multiple of 8; never straddles domain edge
  const bool id = (lg < 7) && (gr >= 0) && (gr < NXg) && (gc >= 0) && (gc < NYg);
  const bool til = (lr >= KSTEP) && (lr < KSTEP + TS) && (lg >= 2) && (lg < 5);
  // Does this block's EXT tile contain the point source? (uniform per block)
  const bool hs = (SRC_X >= r0) && (SRC_X < r0 + EXT) &&
                  (SRC_Y >= c0) && (SRC_Y < c0 + EXT);
  const int gofs = id ? (gr * NYg + gc) : 0;

  const float4 z4 = make_float4(0.f, 0.f, 0.f, 0.f);

  // ---- 1. Issue ALL global loads up front (latency overlaps the rest). ----
  float4 cv0 = z4, cv1 = z4, bv0 = z4, bv1 = z4;
  float4 yc0 = z4, yc1 = z4, yp0 = z4, yp1 = z4;
  if (id) {
    cv0 = *(const float4*)(cgp + gofs);
    cv1 = *(const float4*)(cgp + gofs + 4);
    bv0 = *(const float4*)(bgp + gofs);
    bv1 = *(const float4*)(bgp + gofs + 4);
    if (t0 > 0) {
      yc0 = *(const float4*)(out + obase + (t0 - 1) * CELLS + gofs);
      yc1 = *(const float4*)(out + obase + (t0 - 1) * CELLS + gofs + 4);
      yp0 = *(const float4*)(out + obase + (t0 - 2) * CELLS + gofs);
      yp1 = *(const float4*)(out + obase + (t0 - 2) * CELLS + gofs + 4);
    }
  }
  float xs[KSTEP];
  {
    const float4* xp = (const float4*)(x + bb * TSTEPS + t0);
    float4 a0 = xp[0], a1 = xp[1], a2 = xp[2], a3 = xp[3];
    xs[0] = a0.x; xs[1] = a0.y; xs[2] = a0.z; xs[3] = a0.w;
    xs[4] = a1.x; xs[5] = a1.y; xs[6] = a1.z; xs[7] = a1.w;
    xs[8] = a2.x; xs[9] = a2.y; xs[10] = a2.z; xs[11] = a2.w;
    xs[12] = a3.x; xs[13] = a3.y; xs[14] = a3.z; xs[15] = a3.w;
  }

  // ---- 2. Fused coefficients (overlaps load latency). ----
  // val = Dc*yc - Ey*yp + G*(sum4 - 4*yc) [+ sm*xt]
  // !id lanes keep Dc=Ey=G=0 -> val identically 0 (zero padding / zero lane).
  float4 Dc0 = z4, Dc1 = z4, Ey0 = z4, Ey1 = z4, G0 = z4, G1 = z4;
  float4 sm0 = z4, sm1 = z4;
  if (id) {
    float ai;
    ai = 1.0f / (1.0e6f + 500.0f * bv0.x);
    Dc0.x = 2.0e6f * ai; Ey0.x = (1.0e6f - 500.0f * bv0.x) * ai;
    G0.x = (cv0.x * cv0.x) * inv_h2 * ai;
    ai = 1.0f / (1.0e6f + 500.0f * bv0.y);
    Dc0.y = 2.0e6f * ai; Ey0.y = (1.0e6f - 500.0f * bv0.y) * ai;
    G0.y = (cv0.y * cv0.y) * inv_h2 * ai;
    ai = 1.0f / (1.0e6f + 500.0f * bv0.z);
    Dc0.z = 2.0e6f * ai; Ey0.z = (1.0e6f - 500.0f * bv0.z) * ai;
    G0.z = (cv0.z * cv0.z) * inv_h2 * ai;
    ai = 1.0f / (1.0e6f + 500.0f * bv0.w);
    Dc0.w = 2.0e6f * ai; Ey0.w = (1.0e6f - 500.0f * bv0.w) * ai;
    G0.w = (cv0.w * cv0.w) * inv_h2 * ai;
    ai = 1.0f / (1.0e6f + 500.0f * bv1.x);
    Dc1.x = 2.0e6f * ai; Ey1.x = (1.0e6f - 500.0f * bv1.x) * ai;
    G1.x = (cv1.x * cv1.x) * inv_h2 * ai;
    ai = 1.0f / (1.0e6f + 500.0f * bv1.y);
    Dc1.y = 2.0e6f * ai; Ey1.y = (1.0e6f - 500.0f * bv1.y) * ai;
    G1.y = (cv1.y * cv1.y) * inv_h2 * ai;
    ai = 1.0f / (1.0e6f + 500.0f * bv1.z);
    Dc1.z = 2.0e6f * ai; Ey1.z = (1.0e6f - 500.0f * bv1.z) * ai;
    G1.z = (cv1.z * cv1.z) * inv_h2 * ai;
    ai = 1.0f / (1.0e6f + 500.0f * bv1.w);
    Dc1.w = 2.0e6f * ai; Ey1.w = (1.0e6f - 500.0f * bv1.w) * ai;
    G1.w = (cv1.w * cv1.w) * inv_h2 * ai;
    if (gr == SRC_X) {
      sm0.x = (gc + 0 == SRC_Y) ? 1.0f : 0.0f;
      sm0.y = (gc + 1 == SRC_Y) ? 1.0f : 0.0f;
      sm0.z = (gc + 2 == SRC_Y) ? 1.0f : 0.0f;
      sm0.w = (gc + 3 == SRC_Y) ? 1.0f : 0.0f;
      sm1.x = (gc + 4 == SRC_Y) ? 1.0f : 0.0f;
      sm1.y = (gc + 5 == SRC_Y) ? 1.0f : 0.0f;
      sm1.z = (gc + 6 == SRC_Y) ? 1.0f : 0.0f;
      sm1.w = (gc + 7 == SRC_Y) ? 1.0f : 0.0f;
    }
  }

  // ---- 3. Scatter y(t-1) into buf0 rows 1..56. Guard rows are never read
  //         (row gating keeps lr==0 / lr==55 dead), so no zeroing needed. ----
  const int lo = (lr + 1) * LPITCH + 4 + 8 * lg;
  *(float4*)&buf0[lo] = yc0;
  *(float4*)&buf0[lo + 4] = yc1;
  __syncthreads();  // single prologue barrier

  float* ping = buf0;
  float* pong = buf1;

  // Pipelined output store state.
  float4 pv0 = z4, pv1 = z4;
  float* pop = out;  // dummy; only used when j>0

#define CELL(dst, up_, dn_, lf_, rt_, D_, E_, Gc_, y_, p_)              \
  {                                                                     \
    float s_ = fmaf(-4.0f, y_, (up_ + dn_) + (lf_ + rt_));              \
    dst = fmaf(Gc_, s_, fmaf(-E_, p_, D_ * y_));                        \
  }

#pragma unroll
  for (int j = 0; j < KSTEP; ++j) {
    const float xt = xs[j];
    float* op = out + obase + (t0 + j) * CELLS;

    // Store PREVIOUS step's output now: a full step of work separates this
    // store from the next barrier's vmcnt(0) drain.
    if (j > 0 && til) {
      *(float4*)(pop + gofs) = pv0;
      *(float4*)(pop + gofs + 4) = pv1;
    }

    // Trapezoid gating: step j only needs rows [j+1, 54-j]. j is a
    // compile-time constant (full unroll) -> waves whose 8 rows are all
    // dead skip the whole body via execz.
    const bool alive = (lr >= j + 1) && (lr <= 54 - j);
    if (alive) {
      // Left/right edge neighbors from register state of adjacent lanes.
      float lqw = __shfl_up(yc1.w, 1);
      lqw = (lg == 0) ? 0.0f : lqw;       // row's left edge neighbor is 0
      float rqx = __shfl_down(yc0.x, 1);  // lg==6 pulls zero lane lg==7 -> 0
      rqx = (lg == 7) ? 0.0f : rqx;       // lg==7's source may be exec-masked

      float4 up0 = *(float4*)&ping[lo - LPITCH];
      float4 up1 = *(float4*)&ping[lo - LPITCH + 4];
      float4 dn0 = *(float4*)&ping[lo + LPITCH];
      float4 dn1 = *(float4*)&ping[lo + LPITCH + 4];

      float4 val0, val1;
      CELL(val0.x, up0.x, dn0.x, lqw,    yc0.y, Dc0.x, Ey0.x, G0.x, yc0.x, yp0.x);
      CELL(val0.y, up0.y, dn0.y, yc0.x,  yc0.z, Dc0.y, Ey0.y, G0.y, yc0.y, yp0.y);
      CELL(val0.z, up0.z, dn0.z, yc0.y,  yc0.w, Dc0.z, Ey0.z, G0.z, yc0.z, yp0.z);
      CELL(val0.w, up0.w, dn0.w, yc0.z,  yc1.x, Dc0.w, Ey0.w, G0.w, yc0.w, yp0.w);
      CELL(val1.x, up1.x, dn1.x, yc0.w,  yc1.y, Dc1.x, Ey1.x, G1.x, yc1.x, yp1.x);
      CELL(val1.y, up1.y, dn1.y, yc1.x,  yc1.z, Dc1.y, Ey1.y, G1.y, yc1.y, yp1.y);
      CELL(val1.z, up1.z, dn1.z, yc1.y,  yc1.w, Dc1.z, Ey1.z, G1.z, yc1.z, yp1.z);
      CELL(val1.w, up1.w, dn1.w, yc1.z,  rqx,   Dc1.w, Ey1.w, G1.w, yc1.w, yp1.w);

      if (hs) {  // uniform: only blocks whose EXT tile contains the source
        val0.x = fmaf(sm0.x, xt, val0.x);
        val0.y = fmaf(sm0.y, xt, val0.y);
        val0.z = fmaf(sm0.z, xt, val0.z);
        val0.w = fmaf(sm0.w, xt, val0.w);
        val1.x = fmaf(sm1.x, xt, val1.x);
        val1.y = fmaf(sm1.y, xt, val1.y);
        val1.z = fmaf(sm1.z, xt, val1.z);
        val1.w = fmaf(sm1.w, xt, val1.w);
      }

      yp0 = yc0; yp1 = yc1;
      yc0 = val0; yc1 = val1;

      *(float4*)&pong[lo] = val0;      // lg==7 writes 0 into right pad
      *(float4*)&pong[lo + 4] = val1;

      pv0 = val0; pv1 = val1;
    }
    pop = op;

    __syncthreads();
    float* tmp = ping; ping = pong; pong = tmp;
  }
#undef CELL

  // Final step's output store (drains at kernel end).
  if (til) {
    *(float4*)(pop + gofs) = pv0;
    *(float4*)(pop + gofs + 4) = pv1;
  }
}

extern "C" void kernel_launch(void* const* d_in, const int* in_sizes, int n_in,
                              void* d_out, int out_size, void* d_ws,
                              size_t ws_size, hipStream_t stream) {
  const float* x = (const float*)d_in[0];  // [B, T, 1]
  const float* c = (const float*)d_in[1];  // [192,192]
  const float* b = (const float*)d_in[2];  // [192,192]
  float* out = (float*)d_out;              // [B, T, 192, 192]

  dim3 grid(NXg / TS, NYg / TS, BATCH);  // 8 x 8 x 4 = 256 blocks
  for (int t0 = 0; t0 < TSTEPS; t0 += KSTEP) {
    wave_tile_kernel<<<grid, NTHREADS, 0, stream>>>(c, b, x, out, t0);
  }
}

// Round 2
// 317.937 us; speedup vs baseline: 1.0197x; 1.0197x over previous
//
#include <hip/hip_runtime.h>

// WaveCell: 16 launches x 16 time steps, temporal blocking with 8-wide
// register patches. Round-8 changes (barrier-drain elimination):
//  - step-loop __syncthreads() replaced by raw "s_waitcnt lgkmcnt(0); s_barrier"
//    (single asm volatile w/ memory clobber). __syncthreads emits
//    s_waitcnt vmcnt(0) lgkmcnt(0) before s_barrier, which drains the 2
//    pipelined global float4 stores EVERY step (~300-900 cyc). The barrier
//    only needs LDS visibility (lgkmcnt); global stores need no intra-kernel
//    ordering (no block reads another block's output within a launch) and
//    cross-launch visibility comes from kernel-completion semantics.
//  - barrier after the final step removed (nothing after it reads LDS)
//  - final step's LDS writes removed (never read)
// Carried from round-7: fused 7-op cell update, uniform source guard,
// trapezoid row-gating, masked lg==7 shuffle.

#define NXg 192
#define NYg 192
#define BATCH 4
#define TSTEPS 256
#define CELLS (NXg * NYg)

#define TS 24                   // output tile side
#define KSTEP 16                // time steps per launch
#define EXT 56                  // TS + 2*KSTEP
#define LROWS (EXT + 2)         // rows 1..56 used; 0/57 never read
#define LPITCH 68               // dwords/row: 4 pad | 56 data | 8 pad; %32==4 spreads banks
#define LSZ (LROWS * LPITCH)
#define NTHREADS 448            // 56 rows x 8 lanes/row = 7 waves

#define SRC_X 96
#define SRC_Y 32

__global__ __launch_bounds__(NTHREADS) void wave_tile_kernel(
    const float* __restrict__ cgp, const float* __restrict__ bgp,
    const float* __restrict__ x, float* __restrict__ out, int t0) {
  __shared__ float buf0[LSZ];
  __shared__ float buf1[LSZ];

  const int tid = threadIdx.x;
  const int lr = tid >> 3;      // local row 0..55
  const int lg = tid & 7;       // 8-wide group in row; lg==7 is the zero lane
  const int bcol = blockIdx.x;  // 0..7
  const int brow = blockIdx.y;  // 0..7
  const int bb = blockIdx.z;    // 0..3
  const int r0 = brow * TS - KSTEP;
  const int c0 = bcol * TS - KSTEP;
  const int obase = bb * TSTEPS * CELLS;
  const float inv_h2 = (float)(1.0 / (2.0 * 1.01 * 1.01 * 1.0e-3 * 1.0e-3));

  const int gr = r0 + lr;
  const int gc = c0 + 8 * lg;  // multiple of 8; never straddles domain edge
  const bool id = (lg < 7) && (gr >= 0) && (gr < NXg) && (gc >= 0) && (gc < NYg);
  const bool til = (lr >= KSTEP) && (lr < KSTEP + TS) && (lg >= 2) && (lg < 5);
  // Does this block's EXT tile contain the point source? (uniform per block)
  const bool hs = (SRC_X >= r0) && (SRC_X < r0 + EXT) &&
                  (SRC_Y >= c0) && (SRC_Y < c0 + EXT);
  const int gofs = id ? (gr * NYg + gc) : 0;

  const float4 z4 = make_float4(0.f, 0.f, 0.f, 0.f);

  // ---- 1. Issue ALL global loads up front (latency overlaps the rest). ----
  float4 cv0 = z4, cv1 = z4, bv0 = z4, bv1 = z4;
  float4 yc0 = z4, yc1 = z4, yp0 = z4, yp1 = z4;
  if (id) {
    cv0 = *(const float4*)(cgp + gofs);
    cv1 = *(const float4*)(cgp + gofs + 4);
    bv0 = *(const float4*)(bgp + gofs);
    bv1 = *(const float4*)(bgp + gofs + 4);
    if (t0 > 0) {
      yc0 = *(const float4*)(out + obase + (t0 - 1) * CELLS + gofs);
      yc1 = *(const float4*)(out + obase + (t0 - 1) * CELLS + gofs + 4);
      yp0 = *(const float4*)(out + obase + (t0 - 2) * CELLS + gofs);
      yp1 = *(const float4*)(out + obase + (t0 - 2) * CELLS + gofs + 4);
    }
  }
  float xs[KSTEP];
  {
    const float4* xp = (const float4*)(x + bb * TSTEPS + t0);
    float4 a0 = xp[0], a1 = xp[1], a2 = xp[2], a3 = xp[3];
    xs[0] = a0.x; xs[1] = a0.y; xs[2] = a0.z; xs[3] = a0.w;
    xs[4] = a1.x; xs[5] = a1.y; xs[6] = a1.z; xs[7] = a1.w;
    xs[8] = a2.x; xs[9] = a2.y; xs[10] = a2.z; xs[11] = a2.w;
    xs[12] = a3.x; xs[13] = a3.y; xs[14] = a3.z; xs[15] = a3.w;
  }

  // ---- 2. Fused coefficients (overlaps load latency). ----
  // val = Dc*yc - Ey*yp + G*(sum4 - 4*yc) [+ sm*xt]
  // !id lanes keep Dc=Ey=G=0 -> val identically 0 (zero padding / zero lane).
  float4 Dc0 = z4, Dc1 = z4, Ey0 = z4, Ey1 = z4, G0 = z4, G1 = z4;
  float4 sm0 = z4, sm1 = z4;
  if (id) {
    float ai;
    ai = 1.0f / (1.0e6f + 500.0f * bv0.x);
    Dc0.x = 2.0e6f * ai; Ey0.x = (1.0e6f - 500.0f * bv0.x) * ai;
    G0.x = (cv0.x * cv0.x) * inv_h2 * ai;
    ai = 1.0f / (1.0e6f + 500.0f * bv0.y);
    Dc0.y = 2.0e6f * ai; Ey0.y = (1.0e6f - 500.0f * bv0.y) * ai;
    G0.y = (cv0.y * cv0.y) * inv_h2 * ai;
    ai = 1.0f / (1.0e6f + 500.0f * bv0.z);
    Dc0.z = 2.0e6f * ai; Ey0.z = (1.0e6f - 500.0f * bv0.z) * ai;
    G0.z = (cv0.z * cv0.z) * inv_h2 * ai;
    ai = 1.0f / (1.0e6f + 500.0f * bv0.w);
    Dc0.w = 2.0e6f * ai; Ey0.w = (1.0e6f - 500.0f * bv0.w) * ai;
    G0.w = (cv0.w * cv0.w) * inv_h2 * ai;
    ai = 1.0f / (1.0e6f + 500.0f * bv1.x);
    Dc1.x = 2.0e6f * ai; Ey1.x = (1.0e6f - 500.0f * bv1.x) * ai;
    G1.x = (cv1.x * cv1.x) * inv_h2 * ai;
    ai = 1.0f / (1.0e6f + 500.0f * bv1.y);
    Dc1.y = 2.0e6f * ai; Ey1.y = (1.0e6f - 500.0f * bv1.y) * ai;
    G1.y = (cv1.y * cv1.y) * inv_h2 * ai;
    ai = 1.0f / (1.0e6f + 500.0f * bv1.z);
    Dc1.z = 2.0e6f * ai; Ey1.z = (1.0e6f - 500.0f * bv1.z) * ai;
    G1.z = (cv1.z * cv1.z) * inv_h2 * ai;
    ai = 1.0f / (1.0e6f + 500.0f * bv1.w);
    Dc1.w = 2.0e6f * ai; Ey1.w = (1.0e6f - 500.0f * bv1.w) * ai;
    G1.w = (cv1.w * cv1.w) * inv_h2 * ai;
    if (gr == SRC_X) {
      sm0.x = (gc + 0 == SRC_Y) ? 1.0f : 0.0f;
      sm0.y = (gc + 1 == SRC_Y) ? 1.0f : 0.0f;
      sm0.z = (gc + 2 == SRC_Y) ? 1.0f : 0.0f;
      sm0.w = (gc + 3 == SRC_Y) ? 1.0f : 0.0f;
      sm1.x = (gc + 4 == SRC_Y) ? 1.0f : 0.0f;
      sm1.y = (gc + 5 == SRC_Y) ? 1.0f : 0.0f;
      sm1.z = (gc + 6 == SRC_Y) ? 1.0f : 0.0f;
      sm1.w = (gc + 7 == SRC_Y) ? 1.0f : 0.0f;
    }
  }

  // ---- 3. Scatter y(t-1) into buf0 rows 1..56. Guard rows are never read
  //         (row gating keeps lr==0 / lr==55 dead), so no zeroing needed. ----
  const int lo = (lr + 1) * LPITCH + 4 + 8 * lg;
  *(float4*)&buf0[lo] = yc0;
  *(float4*)&buf0[lo + 4] = yc1;
  __syncthreads();  // single prologue barrier (vmcnt already drained by uses)

  float* ping = buf0;
  float* pong = buf1;

  // Pipelined output store state.
  float4 pv0 = z4, pv1 = z4;
  float* pop = out;  // dummy; only used when j>0

#define CELL(dst, up_, dn_, lf_, rt_, D_, E_, Gc_, y_, p_)              \
  {                                                                     \
    float s_ = fmaf(-4.0f, y_, (up_ + dn_) + (lf_ + rt_));              \
    dst = fmaf(Gc_, s_, fmaf(-E_, p_, D_ * y_));                        \
  }

#pragma unroll
  for (int j = 0; j < KSTEP; ++j) {
    const float xt = xs[j];
    float* op = out + obase + (t0 + j) * CELLS;

    // Store PREVIOUS step's output now. With the lgkm-only barrier these
    // stores are never drained inside the loop; they retire at kernel end.
    if (j > 0 && til) {
      *(float4*)(pop + gofs) = pv0;
      *(float4*)(pop + gofs + 4) = pv1;
    }

    // Trapezoid gating: step j only needs rows [j+1, 54-j]. j is a
    // compile-time constant (full unroll) -> waves whose 8 rows are all
    // dead skip the whole body via execz.
    const bool alive = (lr >= j + 1) && (lr <= 54 - j);
    if (alive) {
      // Left/right edge neighbors from register state of adjacent lanes.
      float lqw = __shfl_up(yc1.w, 1);
      lqw = (lg == 0) ? 0.0f : lqw;       // row's left edge neighbor is 0
      float rqx = __shfl_down(yc0.x, 1);  // lg==6 pulls zero lane lg==7 -> 0
      rqx = (lg == 7) ? 0.0f : rqx;       // lg==7's source may be exec-masked

      float4 up0 = *(float4*)&ping[lo - LPITCH];
      float4 up1 = *(float4*)&ping[lo - LPITCH + 4];
      float4 dn0 = *(float4*)&ping[lo + LPITCH];
      float4 dn1 = *(float4*)&ping[lo + LPITCH + 4];

      float4 val0, val1;
      CELL(val0.x, up0.x, dn0.x, lqw,    yc0.y, Dc0.x, Ey0.x, G0.x, yc0.x, yp0.x);
      CELL(val0.y, up0.y, dn0.y, yc0.x,  yc0.z, Dc0.y, Ey0.y, G0.y, yc0.y, yp0.y);
      CELL(val0.z, up0.z, dn0.z, yc0.y,  yc0.w, Dc0.z, Ey0.z, G0.z, yc0.z, yp0.z);
      CELL(val0.w, up0.w, dn0.w, yc0.z,  yc1.x, Dc0.w, Ey0.w, G0.w, yc0.w, yp0.w);
      CELL(val1.x, up1.x, dn1.x, yc0.w,  yc1.y, Dc1.x, Ey1.x, G1.x, yc1.x, yp1.x);
      CELL(val1.y, up1.y, dn1.y, yc1.x,  yc1.z, Dc1.y, Ey1.y, G1.y, yc1.y, yp1.y);
      CELL(val1.z, up1.z, dn1.z, yc1.y,  yc1.w, Dc1.z, Ey1.z, G1.z, yc1.z, yp1.z);
      CELL(val1.w, up1.w, dn1.w, yc1.z,  rqx,   Dc1.w, Ey1.w, G1.w, yc1.w, yp1.w);

      if (hs) {  // uniform: only blocks whose EXT tile contains the source
        val0.x = fmaf(sm0.x, xt, val0.x);
        val0.y = fmaf(sm0.y, xt, val0.y);
        val0.z = fmaf(sm0.z, xt, val0.z);
        val0.w = fmaf(sm0.w, xt, val0.w);
        val1.x = fmaf(sm1.x, xt, val1.x);
        val1.y = fmaf(sm1.y, xt, val1.y);
        val1.z = fmaf(sm1.z, xt, val1.z);
        val1.w = fmaf(sm1.w, xt, val1.w);
      }

      yp0 = yc0; yp1 = yc1;
      yc0 = val0; yc1 = val1;

      if (j < KSTEP - 1) {           // final step's LDS state is never read
        *(float4*)&pong[lo] = val0;  // lg==7 writes 0 into right pad
        *(float4*)&pong[lo + 4] = val1;
      }

      pv0 = val0; pv1 = val1;
    }
    pop = op;

    if (j < KSTEP - 1) {
      // lgkm-only barrier: orders LDS ping/pong across waves WITHOUT the
      // vmcnt(0) global-store drain that __syncthreads would emit.
      asm volatile("s_waitcnt lgkmcnt(0)\n\ts_barrier" ::: "memory");
    }
    float* tmp = ping; ping = pong; pong = tmp;
  }
#undef CELL

  // Final step's output store (drains at kernel end).
  if (til) {
    *(float4*)(pop + gofs) = pv0;
    *(float4*)(pop + gofs + 4) = pv1;
  }
}

extern "C" void kernel_launch(void* const* d_in, const int* in_sizes, int n_in,
                              void* d_out, int out_size, void* d_ws,
                              size_t ws_size, hipStream_t stream) {
  const float* x = (const float*)d_in[0];  // [B, T, 1]
  const float* c = (const float*)d_in[1];  // [192,192]
  const float* b = (const float*)d_in[2];  // [192,192]
  float* out = (float*)d_out;              // [B, T, 192, 192]

  dim3 grid(NXg / TS, NYg / TS, BATCH);  // 8 x 8 x 4 = 256 blocks
  for (int t0 = 0; t0 < TSTEPS; t0 += KSTEP) {
    wave_tile_kernel<<<grid, NTHREADS, 0, stream>>>(c, b, x, out, t0);
  }
}